// Round 2
// 373.681 us; speedup vs baseline: 1.1939x; 1.1939x over previous
//
#include <hip/hip_runtime.h>
#include <hip/hip_bf16.h>
#include <math.h>

// Problem constants
#define Bn 16
#define Cc 256
#define Hh 64
#define Ww 64
#define HW 4096
#define C2 512
#define Pp 65536          // Bn*HW
#define EPSc 1e-5f

typedef __attribute__((ext_vector_type(8))) short short8;
typedef __attribute__((ext_vector_type(4))) float floatx4;

// ---------------------------------------------------------------------------
// Kernel 0: combine weights.
// W1[o,c]  = sum_m w_poly[o,m] * freq_real[m] * w_expand[m,c]
// W1g_b[o,c] = bf16(W1[o,c] * gamma[c]);  bias1[o] = sum_c W1*beta;
// wsum[o] = sum_c W1*gamma
// ---------------------------------------------------------------------------
__global__ __launch_bounds__(256)
void combine_weights(const float* __restrict__ w_expand,
                     const float* __restrict__ freq_real,
                     const float* __restrict__ w_poly,
                     const float* __restrict__ gamma,
                     const float* __restrict__ beta,
                     __hip_bfloat16* __restrict__ W1g_b,
                     float* __restrict__ bias1,
                     float* __restrict__ wsum) {
    int o = blockIdx.x;
    int c = threadIdx.x;
    float acc = 0.f;
    const float* wp = w_poly + (size_t)o * C2;
    for (int m = 0; m < C2; ++m) {
        acc += wp[m] * freq_real[m] * w_expand[(size_t)m * Cc + c];
    }
    float wg = acc * gamma[c];
    W1g_b[(size_t)o * Cc + c] = __float2bfloat16(wg);
    __shared__ float redB[256];
    __shared__ float redG[256];
    redB[c] = acc * beta[c];
    redG[c] = wg;
    __syncthreads();
    for (int s = 128; s > 0; s >>= 1) {
        if (c < s) { redB[c] += redB[c + s]; redG[c] += redG[c + s]; }
        __syncthreads();
    }
    if (c == 0) { bias1[o] = redB[0]; wsum[o] = redG[0]; }
}

// ---------------------------------------------------------------------------
// Kernel 0b: fp32 -> bf16 weight conversion
// ---------------------------------------------------------------------------
__global__ __launch_bounds__(256)
void to_bf16(const float* __restrict__ a, __hip_bfloat16* __restrict__ o, int n) {
    int i = (blockIdx.x * 256 + threadIdx.x) * 4;
    if (i < n) {
        float4 v = *(const float4*)&a[i];
        __hip_bfloat16 r[4];
        r[0] = __float2bfloat16(v.x);
        r[1] = __float2bfloat16(v.y);
        r[2] = __float2bfloat16(v.z);
        r[3] = __float2bfloat16(v.w);
        *(uint2*)&o[i] = *(const uint2*)r;
    }
}

// ---------------------------------------------------------------------------
// Kernel 0c: pad w_dw [512][9] -> [512][12]
// ---------------------------------------------------------------------------
__global__ __launch_bounds__(256)
void pad_dw(const float* __restrict__ w_dw, float* __restrict__ w_dw_p) {
    int i = blockIdx.x * 256 + threadIdx.x;
    if (i < C2 * 12) {
        int k = i / 12, j = i - k * 12;
        w_dw_p[i] = (j < 9) ? w_dw[k * 9 + j] : 0.f;
    }
}

// ---------------------------------------------------------------------------
// Kernel 1: prep_x — read f (NCHW fp32), emit x_bf (NHWC bf16, k-contiguous)
// + per-position LN stats mu/rstd. Block = 64 positions.
// ---------------------------------------------------------------------------
#define XP 264   // LDS row pitch in bf16 (528 B, 16B-aligned, bank-shifted)

__global__ __launch_bounds__(256, 3)
void prep_x(const float* __restrict__ f,
            __hip_bfloat16* __restrict__ x_bf,
            float* __restrict__ muA,
            float* __restrict__ rsA) {
    __shared__ __hip_bfloat16 Bs[64 * XP];    // 33,792 B, [n][k]
    __shared__ float redS[1024], redQ[1024];

    int blk = blockIdx.x;          // 0..1023
    int b = blk >> 6;
    int s0 = (blk & 63) << 6;
    int tid = threadIdx.x;
    int x = tid & 15, g = tid >> 4;

    const float* fb = f + (size_t)b * Cc * HW + s0 + x * 4;

    float4 v0r[8], v1r[8];
#pragma unroll
    for (int it = 0; it < 8; ++it) {
        int c = (it * 16 + g) * 2;
        v0r[it] = *(const float4*)&fb[(size_t)c * HW];
        v1r[it] = *(const float4*)&fb[(size_t)(c + 1) * HW];
    }

    float lsum[4] = {0.f, 0.f, 0.f, 0.f};
    float lsq[4]  = {0.f, 0.f, 0.f, 0.f};
    unsigned* dst = (unsigned*)&Bs[0];
#pragma unroll
    for (int it = 0; it < 8; ++it) {
        int cpair = it * 16 + g;
        float a0[4] = {v0r[it].x, v0r[it].y, v0r[it].z, v0r[it].w};
        float a1[4] = {v1r[it].x, v1r[it].y, v1r[it].z, v1r[it].w};
#pragma unroll
        for (int j = 0; j < 4; ++j) {
            lsum[j] += a0[j] + a1[j];
            lsq[j]  += a0[j] * a0[j] + a1[j] * a1[j];
            __hip_bfloat16 b0 = __float2bfloat16(a0[j]);
            __hip_bfloat16 b1 = __float2bfloat16(a1[j]);
            unsigned pk = ((unsigned)__bfloat16_as_ushort(b1) << 16) |
                          (unsigned)__bfloat16_as_ushort(b0);
            dst[(size_t)(x * 4 + j) * (XP / 2) + cpair] = pk;
        }
    }
#pragma unroll
    for (int j = 0; j < 4; ++j) {
        redS[g * 64 + x * 4 + j] = lsum[j];
        redQ[g * 64 + x * 4 + j] = lsq[j];
    }
    __syncthreads();

    if (tid < 64) {
        float s = 0.f, q = 0.f;
#pragma unroll
        for (int gg = 0; gg < 16; ++gg) {
            s += redS[gg * 64 + tid];
            q += redQ[gg * 64 + tid];
        }
        float m = s * (1.0f / 256.0f);
        int p = blk * 64 + tid;
        muA[p] = m;
        rsA[p] = rsqrtf(q * (1.0f / 256.0f) - m * m + EPSc);
    }

    // coalesced copy LDS -> global NHWC
    int n = tid >> 2, q4 = tid & 3;
    const __hip_bfloat16* src = &Bs[(size_t)n * XP + q4 * 64];
    __hip_bfloat16* gout = x_bf + ((size_t)blk * 64 + n) * Cc + q4 * 64;
#pragma unroll
    for (int i = 0; i < 8; ++i)
        *(uint4*)&gout[i * 8] = *(const uint4*)&src[i * 8];
}

// ---------------------------------------------------------------------------
// Kernel 2: gemm1b — m97-style 2-barrier GEMM, swapped operands.
// D[p][c] = sum_k x_bf[p,k] * W1g_b[c,k];  f5 = (D - mu[p]*wsum[c])*rstd[p]+bias1[c]
// Block: 128 p x 128 c, K=256, BK=32, 4 waves (2x2 of 64x64). f5 NCHW bf16.
// ---------------------------------------------------------------------------
__global__ __launch_bounds__(256, 3)
void gemm1b(const __hip_bfloat16* __restrict__ x_bf,
            const __hip_bfloat16* __restrict__ W1g_b,
            const float* __restrict__ bias1,
            const float* __restrict__ wsum,
            const float* __restrict__ muA,
            const float* __restrict__ rsA,
            __hip_bfloat16* __restrict__ f5) {
    __shared__ __hip_bfloat16 As[128 * 32];   // 8 KB [p-row][32k]
    __shared__ __hip_bfloat16 Ws[128 * 32];   // 8 KB [c-row][32k]

    int flat = blockIdx.x;         // 0..2047
    int ct = flat & 3;
    int pt = flat >> 2;            // 0..511
    int p0 = pt * 128, c0 = ct * 128;
    int tid = threadIdx.x;
    int lane = tid & 63, wave = tid >> 6;
    int col = lane & 15, quad = lane >> 4;
    int wp = wave >> 1, wc = wave & 1;        // wave tile: 64p x 64c

    floatx4 acc[4][4];
#pragma unroll
    for (int i = 0; i < 4; ++i)
#pragma unroll
        for (int j = 0; j < 4; ++j)
            acc[i][j] = (floatx4){0.f, 0.f, 0.f, 0.f};

    int row0 = tid >> 2, part0 = tid & 3;          // staging slot 0
    int idx1 = 256 + tid;
    int row1 = idx1 >> 2, part1 = idx1 & 3;        // staging slot 1

    for (int ks = 0; ks < 8; ++ks) {
        int k0 = ks * 32;
        // global loads (registers) — independent of LDS
        uint4 ga0 = *(const uint4*)&x_bf[((size_t)(p0 + row0)) * Cc + k0 + part0 * 8];
        uint4 ga1 = *(const uint4*)&x_bf[((size_t)(p0 + row1)) * Cc + k0 + part1 * 8];
        uint4 gb0 = *(const uint4*)&W1g_b[((size_t)(c0 + row0)) * Cc + k0 + part0 * 8];
        uint4 gb1 = *(const uint4*)&W1g_b[((size_t)(c0 + row1)) * Cc + k0 + part1 * 8];
        if (ks > 0) __syncthreads();   // all waves done reading previous tile
        *(uint4*)&As[(size_t)row0 * 32 + part0 * 8] = ga0;
        *(uint4*)&As[(size_t)row1 * 32 + part1 * 8] = ga1;
        *(uint4*)&Ws[(size_t)row0 * 32 + part0 * 8] = gb0;
        *(uint4*)&Ws[(size_t)row1 * 32 + part1 * 8] = gb1;
        __syncthreads();

        short8 af[4], bf[4];
#pragma unroll
        for (int i = 0; i < 4; ++i)
            af[i] = *(const short8*)&As[(size_t)(wp * 64 + i * 16 + col) * 32 + quad * 8];
#pragma unroll
        for (int j = 0; j < 4; ++j)
            bf[j] = *(const short8*)&Ws[(size_t)(wc * 64 + j * 16 + col) * 32 + quad * 8];
#pragma unroll
        for (int i = 0; i < 4; ++i)
#pragma unroll
            for (int j = 0; j < 4; ++j)
                acc[i][j] = __builtin_amdgcn_mfma_f32_16x16x32_bf16(af[i], bf[j], acc[i][j], 0, 0, 0);
    }

    // epilogue: affine + packed uint2 stores (4 consecutive positions/lane)
    int b2 = p0 >> 12;
    int sbase = p0 & 4095;
#pragma unroll
    for (int i = 0; i < 4; ++i) {
        int pl = wp * 64 + i * 16 + quad * 4;          // local p of reg 0
        float4 mu4 = *(const float4*)&muA[p0 + pl];
        float4 rs4 = *(const float4*)&rsA[p0 + pl];
        float mu_[4] = {mu4.x, mu4.y, mu4.z, mu4.w};
        float rs_[4] = {rs4.x, rs4.y, rs4.z, rs4.w};
#pragma unroll
        for (int j = 0; j < 4; ++j) {
            int c = c0 + wc * 64 + j * 16 + col;
            float ws_ = wsum[c], bi_ = bias1[c];
            __hip_bfloat16 v4[4];
#pragma unroll
            for (int r = 0; r < 4; ++r) {
                float v = (acc[i][j][r] - mu_[r] * ws_) * rs_[r] + bi_;
                v4[r] = __float2bfloat16(v);
            }
            *(uint2*)&f5[((size_t)b2 * C2 + c) * HW + sbase + pl] = *(const uint2*)v4;
        }
    }
}

// ---------------------------------------------------------------------------
// Kernel 3: fused tail, 64-position tiles (one full W row per block).
// 1024 blocks x 512 threads (8 waves), 2 blocks/CU. Halves per-position
// weight re-reads from L2 vs the 32-position version, doubles per-phase
// MFMA work, and removes all cross-block w-halo loads (row edges are the
// true SAME-padding zero boundaries).
// ---------------------------------------------------------------------------
#define TPITCH 520

__global__ __launch_bounds__(512, 4)
void fused_tail(const __hip_bfloat16* __restrict__ f5,
                const float* __restrict__ w_dw_p,
                const __hip_bfloat16* __restrict__ w_pw_b,
                const __hip_bfloat16* __restrict__ w_final_b,
                const float* __restrict__ f,
                float* __restrict__ out) {
    __shared__ __hip_bfloat16 tT[64 * TPITCH];   // 66,560 B, reused t -> f7

    // XCD-aware swizzle: 8 consecutive flat ids -> 8 XCDs; each XCD owns an
    // 8-row h-band, iterating b slowest so the band's f5 slab stays in its L2.
    int flat = blockIdx.x;         // 0..1023
    int xcd = flat & 7;
    int slot = flat >> 3;          // 0..127
    int hb = slot & 7;
    int b  = slot >> 3;            // 0..15
    int h  = xcd * 8 + hb;

    int tid = threadIdx.x;
    int lane = tid & 63;
    int wave = tid >> 6;           // 0..7
    int col = lane & 15;
    int quad = lane >> 4;

    // ---- phase 0: depthwise 3x3 -> tT[n][k] (bf16), depth-2 pipeline ----
    // thread: 16 w-positions (t4*16..+15) x 1 channel per it; 4 its of 128 ch.
    const __hip_bfloat16* f5b = f5 + (size_t)b * C2 * HW;
    int t4 = tid & 3;
    int kb = tid >> 2;             // 0..127
    int w16 = t4 * 16;

    uint4 curC[3][2], nxtC[3][2];
#pragma unroll
    for (int dy = 0; dy < 3; ++dy) {
        int hh = h + dy - 1;
        if ((unsigned)hh < Hh) {
            const __hip_bfloat16* row = f5b + (size_t)kb * HW + hh * Ww + w16;
            curC[dy][0] = *(const uint4*)&row[0];
            curC[dy][1] = *(const uint4*)&row[8];
        } else {
            curC[dy][0] = make_uint4(0, 0, 0, 0);
            curC[dy][1] = make_uint4(0, 0, 0, 0);
        }
    }

#pragma unroll
    for (int it = 0; it < 4; ++it) {
        int k = it * 128 + kb;
        if (it < 3) {
            int k2 = k + 128;
#pragma unroll
            for (int dy = 0; dy < 3; ++dy) {
                int hh = h + dy - 1;
                if ((unsigned)hh < Hh) {
                    const __hip_bfloat16* row = f5b + (size_t)k2 * HW + hh * Ww + w16;
                    nxtC[dy][0] = *(const uint4*)&row[0];
                    nxtC[dy][1] = *(const uint4*)&row[8];
                } else {
                    nxtC[dy][0] = make_uint4(0, 0, 0, 0);
                    nxtC[dy][1] = make_uint4(0, 0, 0, 0);
                }
            }
        }
        // consume current channel k
        const float4* wd4 = (const float4*)(w_dw_p + (size_t)k * 12);
        float4 wa = wd4[0], wb = wd4[1], wc2 = wd4[2];
        float wreg[9] = {wa.x, wa.y, wa.z, wa.w, wb.x, wb.y, wb.z, wb.w, wc2.x};
        float acc16[16] = {};
#pragma unroll
        for (int dy = 0; dy < 3; ++dy) {
            const __hip_bfloat16* pv = (const __hip_bfloat16*)&curC[dy][0];
            float cv[16];
#pragma unroll
            for (int j = 0; j < 16; ++j) cv[j] = __bfloat162float(pv[j]);
            float l_in = __shfl_up(cv[15], 1);
            float r_in = __shfl_down(cv[0], 1);
            if (t4 == 0) l_in = 0.f;     // w = -1 -> zero pad
            if (t4 == 3) r_in = 0.f;     // w = 64 -> zero pad
            float win[18];
            win[0] = l_in;
#pragma unroll
            for (int j = 0; j < 16; ++j) win[j + 1] = cv[j];
            win[17] = r_in;
#pragma unroll
            for (int j = 0; j < 16; ++j)
                acc16[j] += wreg[dy * 3 + 0] * win[j] +
                            wreg[dy * 3 + 1] * win[j + 1] +
                            wreg[dy * 3 + 2] * win[j + 2];
        }
#pragma unroll
        for (int j = 0; j < 16; ++j)
            tT[(size_t)(w16 + j) * TPITCH + k] = __float2bfloat16(acc16[j]);
        if (it < 3) {
#pragma unroll
            for (int dy = 0; dy < 3; ++dy) {
                curC[dy][0] = nxtC[dy][0];
                curC[dy][1] = nxtC[dy][1];
            }
        }
    }

    // ---- phase 1: g = w_pw @ t; wave = 64 out x 64 pos, A double-buffered ----
    int wm0 = wave * 64;
    const __hip_bfloat16* Ap = w_pw_b + (size_t)(wm0 + col) * C2 + quad * 8;
    short8 a_cur[4], a_nxt[4];
#pragma unroll
    for (int mt = 0; mt < 4; ++mt)
        a_cur[mt] = *(const short8*)(Ap + (size_t)mt * 16 * C2);

    __syncthreads();   // phase 0 done

    floatx4 acc[4][4];
#pragma unroll
    for (int mt = 0; mt < 4; ++mt)
#pragma unroll
        for (int nt = 0; nt < 4; ++nt)
            acc[mt][nt] = (floatx4){0.f, 0.f, 0.f, 0.f};

#pragma unroll
    for (int ks = 0; ks < 16; ++ks) {
        int k0 = ks * 32;
        if (ks < 15) {
#pragma unroll
            for (int mt = 0; mt < 4; ++mt)
                a_nxt[mt] = *(const short8*)(Ap + (size_t)mt * 16 * C2 + k0 + 32);
        }
        short8 bfr[4];
#pragma unroll
        for (int nt = 0; nt < 4; ++nt)
            bfr[nt] = *(const short8*)&tT[(size_t)(nt * 16 + col) * TPITCH + k0 + quad * 8];
#pragma unroll
        for (int mt = 0; mt < 4; ++mt)
#pragma unroll
            for (int nt = 0; nt < 4; ++nt)
                acc[mt][nt] = __builtin_amdgcn_mfma_f32_16x16x32_bf16(a_cur[mt], bfr[nt], acc[mt][nt], 0, 0, 0);
        if (ks < 15) {
#pragma unroll
            for (int mt = 0; mt < 4; ++mt) a_cur[mt] = a_nxt[mt];
        }
    }
    __syncthreads();   // everyone done reading tT

    // ---- gating: f7 = gelu(g)*g -> back into tT ----
#pragma unroll
    for (int mt = 0; mt < 4; ++mt)
#pragma unroll
        for (int nt = 0; nt < 4; ++nt) {
            __hip_bfloat16 v4[4];
#pragma unroll
            for (int r = 0; r < 4; ++r) {
                float v = acc[mt][nt][r];
                float gl = 0.5f * v * (1.0f + erff(v * 0.70710678118f));
                v4[r] = __float2bfloat16(gl * v);
            }
            *(uint2*)&tT[(size_t)(nt * 16 + col) * TPITCH + wm0 + mt * 16 + quad * 4] = *(const uint2*)v4;
        }

    // ---- phase 2: f8 = w_final @ f7; wave = 32 out x 64 pos; residual hoisted ----
    int wm2 = wave * 32;
    const __hip_bfloat16* Af = w_final_b + (size_t)(wm2 + col) * C2 + quad * 8;
    short8 c_cur[2], c_nxt[2];
#pragma unroll
    for (int mt = 0; mt < 2; ++mt)
        c_cur[mt] = *(const short8*)(Af + (size_t)mt * 16 * C2);

    const float* fb = f + (size_t)b * Cc * HW + h * Ww;
    float* ob = out + (size_t)b * Cc * HW + h * Ww;
    float fres[2][4][4];
#pragma unroll
    for (int mt = 0; mt < 2; ++mt)
#pragma unroll
        for (int nt = 0; nt < 4; ++nt)
#pragma unroll
            for (int r = 0; r < 4; ++r) {
                int m = wm2 + mt * 16 + quad * 4 + r;
                int n = nt * 16 + col;
                fres[mt][nt][r] = fb[(size_t)m * HW + n];
            }

    __syncthreads();   // f7 fully written

    floatx4 acc2[2][4];
#pragma unroll
    for (int mt = 0; mt < 2; ++mt)
#pragma unroll
        for (int nt = 0; nt < 4; ++nt)
            acc2[mt][nt] = (floatx4){0.f, 0.f, 0.f, 0.f};

#pragma unroll
    for (int ks = 0; ks < 16; ++ks) {
        int k0 = ks * 32;
        if (ks < 15) {
#pragma unroll
            for (int mt = 0; mt < 2; ++mt)
                c_nxt[mt] = *(const short8*)(Af + (size_t)mt * 16 * C2 + k0 + 32);
        }
        short8 bfr[4];
#pragma unroll
        for (int nt = 0; nt < 4; ++nt)
            bfr[nt] = *(const short8*)&tT[(size_t)(nt * 16 + col) * TPITCH + k0 + quad * 8];
#pragma unroll
        for (int mt = 0; mt < 2; ++mt)
#pragma unroll
            for (int nt = 0; nt < 4; ++nt)
                acc2[mt][nt] = __builtin_amdgcn_mfma_f32_16x16x32_bf16(c_cur[mt], bfr[nt], acc2[mt][nt], 0, 0, 0);
        if (ks < 15) {
#pragma unroll
            for (int mt = 0; mt < 2; ++mt) c_cur[mt] = c_nxt[mt];
        }
    }

    // ---- epilogue: out = f + f8 ----
#pragma unroll
    for (int mt = 0; mt < 2; ++mt)
#pragma unroll
        for (int nt = 0; nt < 4; ++nt)
#pragma unroll
            for (int r = 0; r < 4; ++r) {
                int m = wm2 + mt * 16 + quad * 4 + r;
                int n = nt * 16 + col;
                ob[(size_t)m * HW + n] = fres[mt][nt][r] + acc2[mt][nt][r];
            }
}

// ---------------------------------------------------------------------------
extern "C" void kernel_launch(void* const* d_in, const int* in_sizes, int n_in,
                              void* d_out, int out_size, void* d_ws, size_t ws_size,
                              hipStream_t stream) {
    const float* f         = (const float*)d_in[0];
    const float* ln_gamma  = (const float*)d_in[1];
    const float* ln_beta   = (const float*)d_in[2];
    const float* w_expand  = (const float*)d_in[3];
    const float* freq_real = (const float*)d_in[4];
    // d_in[5] = freq_imag: provably unused (Re((r+ij)*x) for real x = r*x)
    const float* w_poly    = (const float*)d_in[6];
    const float* w_dw      = (const float*)d_in[7];
    const float* w_pw      = (const float*)d_in[8];
    const float* w_final   = (const float*)d_in[9];
    float* out = (float*)d_out;

    // workspace layout (<= ~66 MB, fits prior footprint)
    char* p = (char*)d_ws;
    __hip_bfloat16* f5   = (__hip_bfloat16*)p;  p += (size_t)C2 * Pp * 2;   // 64 MiB
    __hip_bfloat16* x_bf = (__hip_bfloat16*)p;  p += (size_t)Cc * Pp * 2;   // 32 MiB
    __hip_bfloat16* W1g_b = (__hip_bfloat16*)p; p += (size_t)C2 * Cc * 2;
    float* bias1 = (float*)p;                   p += (size_t)C2 * 4;
    float* wsum  = (float*)p;                   p += (size_t)C2 * 4;
    float* muA   = (float*)p;                   p += (size_t)Pp * 4;
    float* rsA   = (float*)p;                   p += (size_t)Pp * 4;
    __hip_bfloat16* w_pw_b    = (__hip_bfloat16*)p;  p += (size_t)C2 * C2 * 2;
    __hip_bfloat16* w_final_b = (__hip_bfloat16*)p;  p += (size_t)Cc * C2 * 2;
    float* w_dw_p = (float*)p;                  p += (size_t)C2 * 12 * 4;

    combine_weights<<<dim3(C2), dim3(256), 0, stream>>>(
        w_expand, freq_real, w_poly, ln_gamma, ln_beta, W1g_b, bias1, wsum);

    to_bf16<<<dim3((C2 * C2 / 4 + 255) / 256), dim3(256), 0, stream>>>(
        w_pw, w_pw_b, C2 * C2);
    to_bf16<<<dim3((Cc * C2 / 4 + 255) / 256), dim3(256), 0, stream>>>(
        w_final, w_final_b, Cc * C2);
    pad_dw<<<dim3((C2 * 12 + 255) / 256), dim3(256), 0, stream>>>(w_dw, w_dw_p);

    prep_x<<<dim3(Pp / 64), dim3(256), 0, stream>>>(f, x_bf, muA, rsA);

    gemm1b<<<dim3(2048), dim3(256), 0, stream>>>(
        x_bf, W1g_b, bias1, wsum, muA, rsA, f5);

    fused_tail<<<dim3(1024), dim3(512), 0, stream>>>(
        f5, w_dw_p, w_pw_b, w_final_b, f, out);
}

// Round 3
// 361.991 us; speedup vs baseline: 1.2325x; 1.0323x over previous
//
#include <hip/hip_runtime.h>
#include <hip/hip_bf16.h>
#include <math.h>

// Problem constants
#define Bn 16
#define Cc 256
#define Hh 64
#define Ww 64
#define HW 4096
#define C2 512
#define Pp 65536          // Bn*HW
#define EPSc 1e-5f

typedef __attribute__((ext_vector_type(8))) short short8;
typedef __attribute__((ext_vector_type(4))) float floatx4;

// ---------------------------------------------------------------------------
// Kernel 0: combine weights.
// W1[o,c]  = sum_m w_poly[o,m] * freq_real[m] * w_expand[m,c]
// W1g_b[o,c] = bf16(W1[o,c] * gamma[c]);  bias1[o] = sum_c W1*beta;
// wsum[o] = sum_c W1*gamma
// ---------------------------------------------------------------------------
__global__ __launch_bounds__(256)
void combine_weights(const float* __restrict__ w_expand,
                     const float* __restrict__ freq_real,
                     const float* __restrict__ w_poly,
                     const float* __restrict__ gamma,
                     const float* __restrict__ beta,
                     __hip_bfloat16* __restrict__ W1g_b,
                     float* __restrict__ bias1,
                     float* __restrict__ wsum) {
    int o = blockIdx.x;
    int c = threadIdx.x;
    float acc = 0.f;
    const float* wp = w_poly + (size_t)o * C2;
    for (int m = 0; m < C2; ++m) {
        acc += wp[m] * freq_real[m] * w_expand[(size_t)m * Cc + c];
    }
    float wg = acc * gamma[c];
    W1g_b[(size_t)o * Cc + c] = __float2bfloat16(wg);
    __shared__ float redB[256];
    __shared__ float redG[256];
    redB[c] = acc * beta[c];
    redG[c] = wg;
    __syncthreads();
    for (int s = 128; s > 0; s >>= 1) {
        if (c < s) { redB[c] += redB[c + s]; redG[c] += redG[c + s]; }
        __syncthreads();
    }
    if (c == 0) { bias1[o] = redB[0]; wsum[o] = redG[0]; }
}

// ---------------------------------------------------------------------------
// Kernel 0b: fp32 -> bf16 weight conversion
// ---------------------------------------------------------------------------
__global__ __launch_bounds__(256)
void to_bf16(const float* __restrict__ a, __hip_bfloat16* __restrict__ o, int n) {
    int i = (blockIdx.x * 256 + threadIdx.x) * 4;
    if (i < n) {
        float4 v = *(const float4*)&a[i];
        __hip_bfloat16 r[4];
        r[0] = __float2bfloat16(v.x);
        r[1] = __float2bfloat16(v.y);
        r[2] = __float2bfloat16(v.z);
        r[3] = __float2bfloat16(v.w);
        *(uint2*)&o[i] = *(const uint2*)r;
    }
}

// ---------------------------------------------------------------------------
// Kernel 0c: pad w_dw [512][9] -> [512][12]
// ---------------------------------------------------------------------------
__global__ __launch_bounds__(256)
void pad_dw(const float* __restrict__ w_dw, float* __restrict__ w_dw_p) {
    int i = blockIdx.x * 256 + threadIdx.x;
    if (i < C2 * 12) {
        int k = i / 12, j = i - k * 12;
        w_dw_p[i] = (j < 9) ? w_dw[k * 9 + j] : 0.f;
    }
}

// ---------------------------------------------------------------------------
// Kernel 1 (fused prep+gemm): gemm1f — one block per (b,h) row.
// Stages A = f[b, :, h*64..h*64+63] (fp32->bf16) into LDS while accumulating
// LN sum/sumsq (stats are only needed in the epilogue affine), then a
// barrier-free K-loop: B = W1g_b streamed from L2 into registers
// (double-buffered), A fragments from LDS.
// D[n][c] = sum_k x[n,k]*W1g[c,k];  f5 = (D - mu[n]*wsum[c])*rstd[n] + bias1[c]
// Replaces prep_x + gemm1b: kills the 32MB x_bf write + 128MB re-read and
// the 16-barrier short-K GEMM loop.
// ---------------------------------------------------------------------------
#define XPAD 264   // LDS row pitch in bf16 (528 B = 33*16, 16B-aligned)

__global__ __launch_bounds__(512, 4)
void gemm1f(const float* __restrict__ f,
            const __hip_bfloat16* __restrict__ W1g_b,
            const float* __restrict__ bias1,
            const float* __restrict__ wsum,
            __hip_bfloat16* __restrict__ f5) {
    __shared__ __hip_bfloat16 As[64 * XPAD];   // 33,792 B  [n][k]
    __shared__ float redS[32 * 64];            // 8 KB
    __shared__ float redQ[32 * 64];            // 8 KB
    __shared__ float muS[64];
    __shared__ float rsS[64];

    int flat = blockIdx.x;       // 0..1023
    int b = flat >> 6;
    int h = flat & 63;
    int s0 = h * 64;

    int tid = threadIdx.x;
    int x = tid & 15;            // n-quad: positions x*4..x*4+3
    int cg = tid >> 4;           // 0..31 channel-pair group

    // ---- stage A + LN stats ----
    const float* fb = f + (size_t)b * Cc * HW + s0 + x * 4;
    unsigned* Asu = (unsigned*)&As[0];

    float lsum[4] = {0.f, 0.f, 0.f, 0.f};
    float lsq[4]  = {0.f, 0.f, 0.f, 0.f};
#pragma unroll
    for (int i = 0; i < 4; ++i) {
        int cp = i * 32 + cg;    // channel pair 0..127 -> channels 2cp, 2cp+1
        float4 v0 = *(const float4*)&fb[(size_t)(cp * 2) * HW];
        float4 v1 = *(const float4*)&fb[(size_t)(cp * 2 + 1) * HW];
        float a0[4] = {v0.x, v0.y, v0.z, v0.w};
        float a1[4] = {v1.x, v1.y, v1.z, v1.w};
#pragma unroll
        for (int j = 0; j < 4; ++j) {
            lsum[j] += a0[j] + a1[j];
            lsq[j]  += a0[j] * a0[j] + a1[j] * a1[j];
            unsigned pk = ((unsigned)__bfloat16_as_ushort(__float2bfloat16(a1[j])) << 16)
                        |  (unsigned)__bfloat16_as_ushort(__float2bfloat16(a0[j]));
            Asu[(size_t)(x * 4 + j) * (XPAD / 2) + cp] = pk;   // [n][k-pair]
        }
    }
#pragma unroll
    for (int j = 0; j < 4; ++j) {
        redS[cg * 64 + x * 4 + j] = lsum[j];
        redQ[cg * 64 + x * 4 + j] = lsq[j];
    }

    // ---- first B prefetch (independent of LDS; issue before barrier) ----
    int lane = tid & 63, wave = tid >> 6;     // 8 waves
    int col = lane & 15, quad = lane >> 4;
    int c0w = wave * 64;                      // wave owns c0w..c0w+63 x all 64 pos
    const __hip_bfloat16* Bp = W1g_b + (size_t)(c0w + col) * Cc + quad * 8;
    short8 b_cur[4], b_nxt[4];
#pragma unroll
    for (int j = 0; j < 4; ++j)
        b_cur[j] = *(const short8*)(Bp + (size_t)j * 16 * Cc);

    __syncthreads();
    if (tid < 64) {
        float s = 0.f, q = 0.f;
#pragma unroll
        for (int g = 0; g < 32; ++g) { s += redS[g * 64 + tid]; q += redQ[g * 64 + tid]; }
        float m = s * (1.0f / 256.0f);
        muS[tid] = m;
        rsS[tid] = rsqrtf(q * (1.0f / 256.0f) - m * m + EPSc);
    }
    __syncthreads();

    // ---- barrier-free K-loop ----
    floatx4 acc[4][4];
#pragma unroll
    for (int i = 0; i < 4; ++i)
#pragma unroll
        for (int j = 0; j < 4; ++j)
            acc[i][j] = (floatx4){0.f, 0.f, 0.f, 0.f};

#pragma unroll
    for (int ks = 0; ks < 8; ++ks) {
        int k0 = ks * 32;
        if (ks < 7) {
#pragma unroll
            for (int j = 0; j < 4; ++j)
                b_nxt[j] = *(const short8*)(Bp + (size_t)j * 16 * Cc + k0 + 32);
        }
        short8 af[4];
#pragma unroll
        for (int i = 0; i < 4; ++i)
            af[i] = *(const short8*)&As[(size_t)(i * 16 + col) * XPAD + k0 + quad * 8];
#pragma unroll
        for (int i = 0; i < 4; ++i)
#pragma unroll
            for (int j = 0; j < 4; ++j)
                acc[i][j] = __builtin_amdgcn_mfma_f32_16x16x32_bf16(af[i], b_cur[j], acc[i][j], 0, 0, 0);
        if (ks < 7) {
#pragma unroll
            for (int j = 0; j < 4; ++j) b_cur[j] = b_nxt[j];
        }
    }

    // ---- epilogue: affine + packed uint2 stores ----
    __hip_bfloat16* f5b = f5 + (size_t)b * C2 * HW + s0;
#pragma unroll
    for (int i = 0; i < 4; ++i) {
        int pl = i * 16 + quad * 4;          // local pos of reg 0
        float4 mu4 = *(const float4*)&muS[pl];
        float4 rs4 = *(const float4*)&rsS[pl];
        float mu_[4] = {mu4.x, mu4.y, mu4.z, mu4.w};
        float rs_[4] = {rs4.x, rs4.y, rs4.z, rs4.w};
#pragma unroll
        for (int j = 0; j < 4; ++j) {
            int c = c0w + j * 16 + col;
            float ws_ = wsum[c], bi_ = bias1[c];
            __hip_bfloat16 v4[4];
#pragma unroll
            for (int r = 0; r < 4; ++r) {
                float v = (acc[i][j][r] - mu_[r] * ws_) * rs_[r] + bi_;
                v4[r] = __float2bfloat16(v);
            }
            *(uint2*)&f5b[(size_t)c * HW + pl] = *(const uint2*)v4;
        }
    }
}

// ---------------------------------------------------------------------------
// Kernel 3: fused tail, 64-position tiles (one full W row per block).
// 1024 blocks x 512 threads (8 waves), 2 blocks/CU.
// ---------------------------------------------------------------------------
#define TPITCH 520

__global__ __launch_bounds__(512, 4)
void fused_tail(const __hip_bfloat16* __restrict__ f5,
                const float* __restrict__ w_dw_p,
                const __hip_bfloat16* __restrict__ w_pw_b,
                const __hip_bfloat16* __restrict__ w_final_b,
                const float* __restrict__ f,
                float* __restrict__ out) {
    __shared__ __hip_bfloat16 tT[64 * TPITCH];   // 66,560 B, reused t -> f7

    // XCD-aware swizzle: 8 consecutive flat ids -> 8 XCDs; each XCD owns an
    // 8-row h-band, iterating b slowest so the band's f5 slab stays in its L2.
    int flat = blockIdx.x;         // 0..1023
    int xcd = flat & 7;
    int slot = flat >> 3;          // 0..127
    int hb = slot & 7;
    int b  = slot >> 3;            // 0..15
    int h  = xcd * 8 + hb;

    int tid = threadIdx.x;
    int lane = tid & 63;
    int wave = tid >> 6;           // 0..7
    int col = lane & 15;
    int quad = lane >> 4;

    // ---- phase 0: depthwise 3x3 -> tT[n][k] (bf16), depth-2 pipeline ----
    const __hip_bfloat16* f5b = f5 + (size_t)b * C2 * HW;
    int t4 = tid & 3;
    int kb = tid >> 2;             // 0..127
    int w16 = t4 * 16;

    uint4 curC[3][2], nxtC[3][2];
#pragma unroll
    for (int dy = 0; dy < 3; ++dy) {
        int hh = h + dy - 1;
        if ((unsigned)hh < Hh) {
            const __hip_bfloat16* row = f5b + (size_t)kb * HW + hh * Ww + w16;
            curC[dy][0] = *(const uint4*)&row[0];
            curC[dy][1] = *(const uint4*)&row[8];
        } else {
            curC[dy][0] = make_uint4(0, 0, 0, 0);
            curC[dy][1] = make_uint4(0, 0, 0, 0);
        }
    }

#pragma unroll
    for (int it = 0; it < 4; ++it) {
        int k = it * 128 + kb;
        if (it < 3) {
            int k2 = k + 128;
#pragma unroll
            for (int dy = 0; dy < 3; ++dy) {
                int hh = h + dy - 1;
                if ((unsigned)hh < Hh) {
                    const __hip_bfloat16* row = f5b + (size_t)k2 * HW + hh * Ww + w16;
                    nxtC[dy][0] = *(const uint4*)&row[0];
                    nxtC[dy][1] = *(const uint4*)&row[8];
                } else {
                    nxtC[dy][0] = make_uint4(0, 0, 0, 0);
                    nxtC[dy][1] = make_uint4(0, 0, 0, 0);
                }
            }
        }
        // consume current channel k
        const float4* wd4 = (const float4*)(w_dw_p + (size_t)k * 12);
        float4 wa = wd4[0], wb = wd4[1], wc2 = wd4[2];
        float wreg[9] = {wa.x, wa.y, wa.z, wa.w, wb.x, wb.y, wb.z, wb.w, wc2.x};
        float acc16[16] = {};
#pragma unroll
        for (int dy = 0; dy < 3; ++dy) {
            const __hip_bfloat16* pv = (const __hip_bfloat16*)&curC[dy][0];
            float cv[16];
#pragma unroll
            for (int j = 0; j < 16; ++j) cv[j] = __bfloat162float(pv[j]);
            float l_in = __shfl_up(cv[15], 1);
            float r_in = __shfl_down(cv[0], 1);
            if (t4 == 0) l_in = 0.f;     // w = -1 -> zero pad
            if (t4 == 3) r_in = 0.f;     // w = 64 -> zero pad
            float win[18];
            win[0] = l_in;
#pragma unroll
            for (int j = 0; j < 16; ++j) win[j + 1] = cv[j];
            win[17] = r_in;
#pragma unroll
            for (int j = 0; j < 16; ++j)
                acc16[j] += wreg[dy * 3 + 0] * win[j] +
                            wreg[dy * 3 + 1] * win[j + 1] +
                            wreg[dy * 3 + 2] * win[j + 2];
        }
#pragma unroll
        for (int j = 0; j < 16; ++j)
            tT[(size_t)(w16 + j) * TPITCH + k] = __float2bfloat16(acc16[j]);
        if (it < 3) {
#pragma unroll
            for (int dy = 0; dy < 3; ++dy) {
                curC[dy][0] = nxtC[dy][0];
                curC[dy][1] = nxtC[dy][1];
            }
        }
    }

    // ---- phase 1: g = w_pw @ t; wave = 64 out x 64 pos, A double-buffered ----
    int wm0 = wave * 64;
    const __hip_bfloat16* Ap = w_pw_b + (size_t)(wm0 + col) * C2 + quad * 8;
    short8 a_cur[4], a_nxt[4];
#pragma unroll
    for (int mt = 0; mt < 4; ++mt)
        a_cur[mt] = *(const short8*)(Ap + (size_t)mt * 16 * C2);

    __syncthreads();   // phase 0 done

    floatx4 acc[4][4];
#pragma unroll
    for (int mt = 0; mt < 4; ++mt)
#pragma unroll
        for (int nt = 0; nt < 4; ++nt)
            acc[mt][nt] = (floatx4){0.f, 0.f, 0.f, 0.f};

#pragma unroll
    for (int ks = 0; ks < 16; ++ks) {
        int k0 = ks * 32;
        if (ks < 15) {
#pragma unroll
            for (int mt = 0; mt < 4; ++mt)
                a_nxt[mt] = *(const short8*)(Ap + (size_t)mt * 16 * C2 + k0 + 32);
        }
        short8 bfr[4];
#pragma unroll
        for (int nt = 0; nt < 4; ++nt)
            bfr[nt] = *(const short8*)&tT[(size_t)(nt * 16 + col) * TPITCH + k0 + quad * 8];
#pragma unroll
        for (int mt = 0; mt < 4; ++mt)
#pragma unroll
            for (int nt = 0; nt < 4; ++nt)
                acc[mt][nt] = __builtin_amdgcn_mfma_f32_16x16x32_bf16(a_cur[mt], bfr[nt], acc[mt][nt], 0, 0, 0);
        if (ks < 15) {
#pragma unroll
            for (int mt = 0; mt < 4; ++mt) a_cur[mt] = a_nxt[mt];
        }
    }
    __syncthreads();   // everyone done reading tT

    // ---- gating: f7 = gelu(g)*g -> back into tT ----
#pragma unroll
    for (int mt = 0; mt < 4; ++mt)
#pragma unroll
        for (int nt = 0; nt < 4; ++nt) {
            __hip_bfloat16 v4[4];
#pragma unroll
            for (int r = 0; r < 4; ++r) {
                float v = acc[mt][nt][r];
                float gl = 0.5f * v * (1.0f + erff(v * 0.70710678118f));
                v4[r] = __float2bfloat16(gl * v);
            }
            *(uint2*)&tT[(size_t)(nt * 16 + col) * TPITCH + wm0 + mt * 16 + quad * 4] = *(const uint2*)v4;
        }

    // ---- phase 2: f8 = w_final @ f7; wave = 32 out x 64 pos; residual hoisted ----
    int wm2 = wave * 32;
    const __hip_bfloat16* Af = w_final_b + (size_t)(wm2 + col) * C2 + quad * 8;
    short8 c_cur[2], c_nxt[2];
#pragma unroll
    for (int mt = 0; mt < 2; ++mt)
        c_cur[mt] = *(const short8*)(Af + (size_t)mt * 16 * C2);

    const float* fb = f + (size_t)b * Cc * HW + h * Ww;
    float* ob = out + (size_t)b * Cc * HW + h * Ww;
    float fres[2][4][4];
#pragma unroll
    for (int mt = 0; mt < 2; ++mt)
#pragma unroll
        for (int nt = 0; nt < 4; ++nt)
#pragma unroll
            for (int r = 0; r < 4; ++r) {
                int m = wm2 + mt * 16 + quad * 4 + r;
                int n = nt * 16 + col;
                fres[mt][nt][r] = fb[(size_t)m * HW + n];
            }

    __syncthreads();   // f7 fully written

    floatx4 acc2[2][4];
#pragma unroll
    for (int mt = 0; mt < 2; ++mt)
#pragma unroll
        for (int nt = 0; nt < 4; ++nt)
            acc2[mt][nt] = (floatx4){0.f, 0.f, 0.f, 0.f};

#pragma unroll
    for (int ks = 0; ks < 16; ++ks) {
        int k0 = ks * 32;
        if (ks < 15) {
#pragma unroll
            for (int mt = 0; mt < 2; ++mt)
                c_nxt[mt] = *(const short8*)(Af + (size_t)mt * 16 * C2 + k0 + 32);
        }
        short8 bfr[4];
#pragma unroll
        for (int nt = 0; nt < 4; ++nt)
            bfr[nt] = *(const short8*)&tT[(size_t)(nt * 16 + col) * TPITCH + k0 + quad * 8];
#pragma unroll
        for (int mt = 0; mt < 2; ++mt)
#pragma unroll
            for (int nt = 0; nt < 4; ++nt)
                acc2[mt][nt] = __builtin_amdgcn_mfma_f32_16x16x32_bf16(c_cur[mt], bfr[nt], acc2[mt][nt], 0, 0, 0);
        if (ks < 15) {
#pragma unroll
            for (int mt = 0; mt < 2; ++mt) c_cur[mt] = c_nxt[mt];
        }
    }

    // ---- epilogue: out = f + f8 ----
#pragma unroll
    for (int mt = 0; mt < 2; ++mt)
#pragma unroll
        for (int nt = 0; nt < 4; ++nt)
#pragma unroll
            for (int r = 0; r < 4; ++r) {
                int m = wm2 + mt * 16 + quad * 4 + r;
                int n = nt * 16 + col;
                ob[(size_t)m * HW + n] = fres[mt][nt][r] + acc2[mt][nt][r];
            }
}

// ---------------------------------------------------------------------------
extern "C" void kernel_launch(void* const* d_in, const int* in_sizes, int n_in,
                              void* d_out, int out_size, void* d_ws, size_t ws_size,
                              hipStream_t stream) {
    const float* f         = (const float*)d_in[0];
    const float* ln_gamma  = (const float*)d_in[1];
    const float* ln_beta   = (const float*)d_in[2];
    const float* w_expand  = (const float*)d_in[3];
    const float* freq_real = (const float*)d_in[4];
    // d_in[5] = freq_imag: provably unused (Re((r+ij)*x) for real x = r*x)
    const float* w_poly    = (const float*)d_in[6];
    const float* w_dw      = (const float*)d_in[7];
    const float* w_pw      = (const float*)d_in[8];
    const float* w_final   = (const float*)d_in[9];
    float* out = (float*)d_out;

    // workspace layout (x_bf / muA / rsA removed — stats are block-local now)
    char* p = (char*)d_ws;
    __hip_bfloat16* f5   = (__hip_bfloat16*)p;  p += (size_t)C2 * Pp * 2;   // 64 MiB
    __hip_bfloat16* W1g_b = (__hip_bfloat16*)p; p += (size_t)C2 * Cc * 2;
    float* bias1 = (float*)p;                   p += (size_t)C2 * 4;
    float* wsum  = (float*)p;                   p += (size_t)C2 * 4;
    __hip_bfloat16* w_pw_b    = (__hip_bfloat16*)p;  p += (size_t)C2 * C2 * 2;
    __hip_bfloat16* w_final_b = (__hip_bfloat16*)p;  p += (size_t)Cc * C2 * 2;
    float* w_dw_p = (float*)p;                  p += (size_t)C2 * 12 * 4;

    combine_weights<<<dim3(C2), dim3(256), 0, stream>>>(
        w_expand, freq_real, w_poly, ln_gamma, ln_beta, W1g_b, bias1, wsum);

    to_bf16<<<dim3((C2 * C2 / 4 + 255) / 256), dim3(256), 0, stream>>>(
        w_pw, w_pw_b, C2 * C2);
    to_bf16<<<dim3((Cc * C2 / 4 + 255) / 256), dim3(256), 0, stream>>>(
        w_final, w_final_b, Cc * C2);
    pad_dw<<<dim3((C2 * 12 + 255) / 256), dim3(256), 0, stream>>>(w_dw, w_dw_p);

    gemm1f<<<dim3(1024), dim3(512), 0, stream>>>(
        f, W1g_b, bias1, wsum, f5);

    fused_tail<<<dim3(1024), dim3(512), 0, stream>>>(
        f5, w_dw_p, w_pw_b, w_final_b, f, out);
}

// Round 4
// 343.381 us; speedup vs baseline: 1.2993x; 1.0542x over previous
//
#include <hip/hip_runtime.h>
#include <hip/hip_bf16.h>
#include <math.h>

// Problem constants
#define Bn 16
#define Cc 256
#define Hh 64
#define Ww 64
#define HW 4096
#define C2 512
#define Pp 65536          // Bn*HW
#define EPSc 1e-5f

typedef __attribute__((ext_vector_type(8))) short short8;
typedef __attribute__((ext_vector_type(4))) float floatx4;

// ---------------------------------------------------------------------------
// Kernel 0: combine weights, split-K (kh=0/1 halves the serial dep chain).
// W1[o,c]  = sum_m w_poly[o,m] * freq_real[m] * w_expand[m,c]
// W1g_b[o,c] = bf16(W1[o,c] * gamma[c]);  bias1[o] = sum_c W1*beta;
// wsum[o] = sum_c W1*gamma
// ---------------------------------------------------------------------------
__global__ __launch_bounds__(512)
void combine_weights(const float* __restrict__ w_expand,
                     const float* __restrict__ freq_real,
                     const float* __restrict__ w_poly,
                     const float* __restrict__ gamma,
                     const float* __restrict__ beta,
                     __hip_bfloat16* __restrict__ W1g_b,
                     float* __restrict__ bias1,
                     float* __restrict__ wsum) {
    int o = blockIdx.x;
    int tid = threadIdx.x;
    int c = tid & 255;
    int kh = tid >> 8;           // 0/1: K-half
    float acc = 0.f;
    const float* wp = w_poly + (size_t)o * C2 + kh * 256;
    const float* fr = freq_real + kh * 256;
    const float* we = w_expand + (size_t)(kh * 256) * Cc + c;
    for (int m = 0; m < 256; ++m) {
        acc += wp[m] * fr[m] * we[(size_t)m * Cc];
    }
    __shared__ float part[512];
    __shared__ float redB[256];
    __shared__ float redG[256];
    part[tid] = acc;
    __syncthreads();
    if (tid < 256) {
        float a = part[tid] + part[tid + 256];
        float wg = a * gamma[c];
        W1g_b[(size_t)o * Cc + c] = __float2bfloat16(wg);
        redB[c] = a * beta[c];
        redG[c] = wg;
    }
    __syncthreads();
    for (int s = 128; s > 0; s >>= 1) {
        if (tid < s) { redB[tid] += redB[tid + s]; redG[tid] += redG[tid + s]; }
        __syncthreads();
    }
    if (tid == 0) { bias1[o] = redB[0]; wsum[o] = redG[0]; }
}

// ---------------------------------------------------------------------------
// Kernel 0b: merged weight prep — w_pw->bf16, w_final->bf16, pad w_dw.
// Grid covers 65536 + 32768 float4-quads then 6144 pad elements.
// ---------------------------------------------------------------------------
__device__ inline void cvt4(const float* __restrict__ a,
                            __hip_bfloat16* __restrict__ o, int q) {
    float4 v = *(const float4*)&a[q * 4];
    __hip_bfloat16 r[4];
    r[0] = __float2bfloat16(v.x);
    r[1] = __float2bfloat16(v.y);
    r[2] = __float2bfloat16(v.z);
    r[3] = __float2bfloat16(v.w);
    *(uint2*)&o[q * 4] = *(const uint2*)r;
}

__global__ __launch_bounds__(256)
void prep_weights(const float* __restrict__ w_pw,
                  const float* __restrict__ w_final,
                  const float* __restrict__ w_dw,
                  __hip_bfloat16* __restrict__ w_pw_b,
                  __hip_bfloat16* __restrict__ w_final_b,
                  float* __restrict__ w_dw_p) {
    int i = blockIdx.x * 256 + threadIdx.x;
    if (i < 65536) {
        cvt4(w_pw, w_pw_b, i);
    } else if (i < 98304) {
        cvt4(w_final, w_final_b, i - 65536);
    } else {
        int j = i - 98304;
        if (j < C2 * 12) {
            int k = j / 12, l = j - k * 12;
            w_dw_p[j] = (l < 9) ? w_dw[k * 9 + l] : 0.f;
        }
    }
}

// ---------------------------------------------------------------------------
// Kernel 1 (fused prep+gemm): gemm1f — one block per (b,h) row.
// Stages A = f[b, :, h*64..h*64+63] (fp32->bf16) into LDS while accumulating
// LN sum/sumsq, then a barrier-free K-loop with DEPTH-2 register prefetch
// of B = W1g_b (L2-resident).
// D[n][c] = sum_k x[n,k]*W1g[c,k];  f5 = (D - mu[n]*wsum[c])*rstd[n] + bias1[c]
// ---------------------------------------------------------------------------
#define XPAD 264   // LDS row pitch in bf16 (528 B = 33*16, 16B-aligned)

__global__ __launch_bounds__(512, 4)
void gemm1f(const float* __restrict__ f,
            const __hip_bfloat16* __restrict__ W1g_b,
            const float* __restrict__ bias1,
            const float* __restrict__ wsum,
            __hip_bfloat16* __restrict__ f5) {
    __shared__ __hip_bfloat16 As[64 * XPAD];   // 33,792 B  [n][k]
    __shared__ float redS[32 * 64];            // 8 KB
    __shared__ float redQ[32 * 64];            // 8 KB
    __shared__ float muS[64];
    __shared__ float rsS[64];

    int flat = blockIdx.x;       // 0..1023
    int b = flat >> 6;
    int h = flat & 63;
    int s0 = h * 64;

    int tid = threadIdx.x;
    int x = tid & 15;            // n-quad: positions x*4..x*4+3
    int cg = tid >> 4;           // 0..31 channel-pair group

    // ---- stage A + LN stats ----
    const float* fb = f + (size_t)b * Cc * HW + s0 + x * 4;
    unsigned* Asu = (unsigned*)&As[0];

    float lsum[4] = {0.f, 0.f, 0.f, 0.f};
    float lsq[4]  = {0.f, 0.f, 0.f, 0.f};
#pragma unroll
    for (int i = 0; i < 4; ++i) {
        int cp = i * 32 + cg;    // channel pair 0..127 -> channels 2cp, 2cp+1
        float4 v0 = *(const float4*)&fb[(size_t)(cp * 2) * HW];
        float4 v1 = *(const float4*)&fb[(size_t)(cp * 2 + 1) * HW];
        float a0[4] = {v0.x, v0.y, v0.z, v0.w};
        float a1[4] = {v1.x, v1.y, v1.z, v1.w};
#pragma unroll
        for (int j = 0; j < 4; ++j) {
            lsum[j] += a0[j] + a1[j];
            lsq[j]  += a0[j] * a0[j] + a1[j] * a1[j];
            unsigned pk = ((unsigned)__bfloat16_as_ushort(__float2bfloat16(a1[j])) << 16)
                        |  (unsigned)__bfloat16_as_ushort(__float2bfloat16(a0[j]));
            Asu[(size_t)(x * 4 + j) * (XPAD / 2) + cp] = pk;   // [n][k-pair]
        }
    }
#pragma unroll
    for (int j = 0; j < 4; ++j) {
        redS[cg * 64 + x * 4 + j] = lsum[j];
        redQ[cg * 64 + x * 4 + j] = lsq[j];
    }

    // ---- initial B prefetch, depth-2 (independent of LDS; before barrier) ----
    int lane = tid & 63, wave = tid >> 6;     // 8 waves
    int col = lane & 15, quad = lane >> 4;
    int c0w = wave * 64;                      // wave owns c0w..c0w+63 x all 64 pos
    const __hip_bfloat16* Bp = W1g_b + (size_t)(c0w + col) * Cc + quad * 8;
    short8 B0[4], B1[4];
#pragma unroll
    for (int j = 0; j < 4; ++j) {
        B0[j] = *(const short8*)(Bp + (size_t)j * 16 * Cc);
        B1[j] = *(const short8*)(Bp + (size_t)j * 16 * Cc + 32);
    }

    // epilogue scalars hoisted (tiny, L2-hot)
    float ws4[4], bi4[4];
#pragma unroll
    for (int j = 0; j < 4; ++j) {
        int c = c0w + j * 16 + col;
        ws4[j] = wsum[c];
        bi4[j] = bias1[c];
    }

    __syncthreads();
    if (tid < 64) {
        float s = 0.f, q = 0.f;
#pragma unroll
        for (int g = 0; g < 32; ++g) { s += redS[g * 64 + tid]; q += redQ[g * 64 + tid]; }
        float m = s * (1.0f / 256.0f);
        muS[tid] = m;
        rsS[tid] = rsqrtf(q * (1.0f / 256.0f) - m * m + EPSc);
    }
    __syncthreads();

    // ---- barrier-free K-loop, depth-2 B prefetch ----
    floatx4 acc[4][4];
#pragma unroll
    for (int i = 0; i < 4; ++i)
#pragma unroll
        for (int j = 0; j < 4; ++j)
            acc[i][j] = (floatx4){0.f, 0.f, 0.f, 0.f};

#pragma unroll
    for (int ks = 0; ks < 8; ++ks) {
        int k0 = ks * 32;
        short8 af[4];
#pragma unroll
        for (int i = 0; i < 4; ++i)
            af[i] = *(const short8*)&As[(size_t)(i * 16 + col) * XPAD + k0 + quad * 8];
        __builtin_amdgcn_s_setprio(1);
#pragma unroll
        for (int i = 0; i < 4; ++i)
#pragma unroll
            for (int j = 0; j < 4; ++j)
                acc[i][j] = __builtin_amdgcn_mfma_f32_16x16x32_bf16(
                    af[i], (ks & 1) ? B1[j] : B0[j], acc[i][j], 0, 0, 0);
        __builtin_amdgcn_s_setprio(0);
        if (ks + 2 < 8) {
#pragma unroll
            for (int j = 0; j < 4; ++j) {
                short8 v = *(const short8*)(Bp + (size_t)j * 16 * Cc + k0 + 64);
                if (ks & 1) B1[j] = v; else B0[j] = v;
            }
        }
    }

    // ---- epilogue: affine + packed uint2 stores ----
    __hip_bfloat16* f5b = f5 + (size_t)b * C2 * HW + s0;
#pragma unroll
    for (int i = 0; i < 4; ++i) {
        int pl = i * 16 + quad * 4;          // local pos of reg 0
        float4 mu4 = *(const float4*)&muS[pl];
        float4 rs4 = *(const float4*)&rsS[pl];
        float mu_[4] = {mu4.x, mu4.y, mu4.z, mu4.w};
        float rs_[4] = {rs4.x, rs4.y, rs4.z, rs4.w};
#pragma unroll
        for (int j = 0; j < 4; ++j) {
            int c = c0w + j * 16 + col;
            __hip_bfloat16 v4[4];
#pragma unroll
            for (int r = 0; r < 4; ++r) {
                float v = (acc[i][j][r] - mu_[r] * ws4[j]) * rs_[r] + bi4[j];
                v4[r] = __float2bfloat16(v);
            }
            *(uint2*)&f5b[(size_t)c * HW + pl] = *(const uint2*)v4;
        }
    }
}

// ---------------------------------------------------------------------------
// Kernel 3: fused tail, 64-position tiles (one full W row per block).
// 1024 blocks x 512 threads (8 waves), 2 blocks/CU. This round: depth-2
// register prefetch in all three phases + s_setprio around MFMA clusters.
// ---------------------------------------------------------------------------
#define TPITCH 520

// depth-2 staging load of one channel-iteration of f5 (3 dy rows x 32 B)
#define P0_LOAD(dst, itc) do {                                               \
    int kk_ = (itc) * 128 + kb;                                              \
    _Pragma("unroll")                                                        \
    for (int dy_ = 0; dy_ < 3; ++dy_) {                                      \
        int hh_ = h + dy_ - 1;                                               \
        if ((unsigned)hh_ < Hh) {                                            \
            const __hip_bfloat16* row_ = f5b + (size_t)kk_ * HW + hh_ * Ww + w16; \
            dst[dy_][0] = *(const uint4*)&row_[0];                           \
            dst[dy_][1] = *(const uint4*)&row_[8];                           \
        } else {                                                             \
            dst[dy_][0] = make_uint4(0, 0, 0, 0);                            \
            dst[dy_][1] = make_uint4(0, 0, 0, 0);                            \
        }                                                                    \
    } } while (0)

__global__ __launch_bounds__(512, 4)
void fused_tail(const __hip_bfloat16* __restrict__ f5,
                const float* __restrict__ w_dw_p,
                const __hip_bfloat16* __restrict__ w_pw_b,
                const __hip_bfloat16* __restrict__ w_final_b,
                const float* __restrict__ f,
                float* __restrict__ out) {
    __shared__ __hip_bfloat16 tT[64 * TPITCH];   // 66,560 B, reused t -> f7

    // XCD-aware swizzle: 8 consecutive flat ids -> 8 XCDs; each XCD owns an
    // 8-row h-band, iterating b slowest so the band's f5 slab stays in its L2.
    int flat = blockIdx.x;         // 0..1023
    int xcd = flat & 7;
    int slot = flat >> 3;          // 0..127
    int hb = slot & 7;
    int b  = slot >> 3;            // 0..15
    int h  = xcd * 8 + hb;

    int tid = threadIdx.x;
    int lane = tid & 63;
    int wave = tid >> 6;           // 0..7
    int col = lane & 15;
    int quad = lane >> 4;

    // ---- phase 0: depthwise 3x3 -> tT[n][k] (bf16), depth-2 pipeline ----
    const __hip_bfloat16* f5b = f5 + (size_t)b * C2 * HW;
    int t4 = tid & 3;
    int kb = tid >> 2;             // 0..127
    int w16 = t4 * 16;

    uint4 bA[3][2], bB[3][2];
    P0_LOAD(bA, 0);
    P0_LOAD(bB, 1);

#pragma unroll
    for (int it = 0; it < 4; ++it) {
        int k = it * 128 + kb;
        const float4* wd4 = (const float4*)(w_dw_p + (size_t)k * 12);
        float4 wa = wd4[0], wb = wd4[1], wc2 = wd4[2];
        float wreg[9] = {wa.x, wa.y, wa.z, wa.w, wb.x, wb.y, wb.z, wb.w, wc2.x};
        float acc16[16] = {};
#pragma unroll
        for (int dy = 0; dy < 3; ++dy) {
            const __hip_bfloat16* pv =
                (const __hip_bfloat16*)((it & 1) ? &bB[dy][0] : &bA[dy][0]);
            float cv[16];
#pragma unroll
            for (int j = 0; j < 16; ++j) cv[j] = __bfloat162float(pv[j]);
            float l_in = __shfl_up(cv[15], 1);
            float r_in = __shfl_down(cv[0], 1);
            if (t4 == 0) l_in = 0.f;     // w = -1 -> zero pad
            if (t4 == 3) r_in = 0.f;     // w = 64 -> zero pad
            float win[18];
            win[0] = l_in;
#pragma unroll
            for (int j = 0; j < 16; ++j) win[j + 1] = cv[j];
            win[17] = r_in;
#pragma unroll
            for (int j = 0; j < 16; ++j)
                acc16[j] += wreg[dy * 3 + 0] * win[j] +
                            wreg[dy * 3 + 1] * win[j + 1] +
                            wreg[dy * 3 + 2] * win[j + 2];
        }
        // issue-after-consume prefetch of channel it+2 (hides ~1 full iter)
        if (it + 2 < 4) {
            if (it & 1) { P0_LOAD(bB, it + 2); } else { P0_LOAD(bA, it + 2); }
        }
#pragma unroll
        for (int j = 0; j < 16; ++j)
            tT[(size_t)(w16 + j) * TPITCH + k] = __float2bfloat16(acc16[j]);
    }

    // ---- phase 1: g = w_pw @ t; wave = 64 out x 64 pos, depth-2 A prefetch ----
    int wm0 = wave * 64;
    const __hip_bfloat16* Ap = w_pw_b + (size_t)(wm0 + col) * C2 + quad * 8;
    short8 A0[4], A1[4];
#pragma unroll
    for (int mt = 0; mt < 4; ++mt)
        A0[mt] = *(const short8*)(Ap + (size_t)mt * 16 * C2);

    __syncthreads();   // phase 0 done

#pragma unroll
    for (int mt = 0; mt < 4; ++mt)
        A1[mt] = *(const short8*)(Ap + (size_t)mt * 16 * C2 + 32);

    floatx4 acc[4][4];
#pragma unroll
    for (int mt = 0; mt < 4; ++mt)
#pragma unroll
        for (int nt = 0; nt < 4; ++nt)
            acc[mt][nt] = (floatx4){0.f, 0.f, 0.f, 0.f};

#pragma unroll
    for (int ks = 0; ks < 16; ++ks) {
        int k0 = ks * 32;
        short8 bfr[4];
#pragma unroll
        for (int nt = 0; nt < 4; ++nt)
            bfr[nt] = *(const short8*)&tT[(size_t)(nt * 16 + col) * TPITCH + k0 + quad * 8];
        __builtin_amdgcn_s_setprio(1);
#pragma unroll
        for (int mt = 0; mt < 4; ++mt)
#pragma unroll
            for (int nt = 0; nt < 4; ++nt)
                acc[mt][nt] = __builtin_amdgcn_mfma_f32_16x16x32_bf16(
                    (ks & 1) ? A1[mt] : A0[mt], bfr[nt], acc[mt][nt], 0, 0, 0);
        __builtin_amdgcn_s_setprio(0);
        if (ks + 2 < 16) {
#pragma unroll
            for (int mt = 0; mt < 4; ++mt) {
                short8 v = *(const short8*)(Ap + (size_t)mt * 16 * C2 + k0 + 64);
                if (ks & 1) A1[mt] = v; else A0[mt] = v;
            }
        }
    }
    __syncthreads();   // everyone done reading tT

    // ---- gating: f7 = gelu(g)*g -> back into tT ----
#pragma unroll
    for (int mt = 0; mt < 4; ++mt)
#pragma unroll
        for (int nt = 0; nt < 4; ++nt) {
            __hip_bfloat16 v4[4];
#pragma unroll
            for (int r = 0; r < 4; ++r) {
                float v = acc[mt][nt][r];
                float gl = 0.5f * v * (1.0f + erff(v * 0.70710678118f));
                v4[r] = __float2bfloat16(gl * v);
            }
            *(uint2*)&tT[(size_t)(nt * 16 + col) * TPITCH + wm0 + mt * 16 + quad * 4] = *(const uint2*)v4;
        }

    // ---- phase 2: f8 = w_final @ f7; wave = 32 out x 64 pos; depth-2 ----
    int wm2 = wave * 32;
    const __hip_bfloat16* Af = w_final_b + (size_t)(wm2 + col) * C2 + quad * 8;
    short8 C0[2], C1[2];
#pragma unroll
    for (int mt = 0; mt < 2; ++mt)
        C0[mt] = *(const short8*)(Af + (size_t)mt * 16 * C2);

    const float* fb = f + (size_t)b * Cc * HW + h * Ww;
    float* ob = out + (size_t)b * Cc * HW + h * Ww;
    float fres[2][4][4];
#pragma unroll
    for (int mt = 0; mt < 2; ++mt)
#pragma unroll
        for (int nt = 0; nt < 4; ++nt)
#pragma unroll
            for (int r = 0; r < 4; ++r) {
                int m = wm2 + mt * 16 + quad * 4 + r;
                int n = nt * 16 + col;
                fres[mt][nt][r] = fb[(size_t)m * HW + n];
            }

    __syncthreads();   // f7 fully written

#pragma unroll
    for (int mt = 0; mt < 2; ++mt)
        C1[mt] = *(const short8*)(Af + (size_t)mt * 16 * C2 + 32);

    floatx4 acc2[2][4];
#pragma unroll
    for (int mt = 0; mt < 2; ++mt)
#pragma unroll
        for (int nt = 0; nt < 4; ++nt)
            acc2[mt][nt] = (floatx4){0.f, 0.f, 0.f, 0.f};

#pragma unroll
    for (int ks = 0; ks < 16; ++ks) {
        int k0 = ks * 32;
        short8 bfr[4];
#pragma unroll
        for (int nt = 0; nt < 4; ++nt)
            bfr[nt] = *(const short8*)&tT[(size_t)(nt * 16 + col) * TPITCH + k0 + quad * 8];
        __builtin_amdgcn_s_setprio(1);
#pragma unroll
        for (int mt = 0; mt < 2; ++mt)
#pragma unroll
            for (int nt = 0; nt < 4; ++nt)
                acc2[mt][nt] = __builtin_amdgcn_mfma_f32_16x16x32_bf16(
                    (ks & 1) ? C1[mt] : C0[mt], bfr[nt], acc2[mt][nt], 0, 0, 0);
        __builtin_amdgcn_s_setprio(0);
        if (ks + 2 < 16) {
#pragma unroll
            for (int mt = 0; mt < 2; ++mt) {
                short8 v = *(const short8*)(Af + (size_t)mt * 16 * C2 + k0 + 64);
                if (ks & 1) C1[mt] = v; else C0[mt] = v;
            }
        }
    }

    // ---- epilogue: out = f + f8 ----
#pragma unroll
    for (int mt = 0; mt < 2; ++mt)
#pragma unroll
        for (int nt = 0; nt < 4; ++nt)
#pragma unroll
            for (int r = 0; r < 4; ++r) {
                int m = wm2 + mt * 16 + quad * 4 + r;
                int n = nt * 16 + col;
                ob[(size_t)m * HW + n] = fres[mt][nt][r] + acc2[mt][nt][r];
            }
}

// ---------------------------------------------------------------------------
extern "C" void kernel_launch(void* const* d_in, const int* in_sizes, int n_in,
                              void* d_out, int out_size, void* d_ws, size_t ws_size,
                              hipStream_t stream) {
    const float* f         = (const float*)d_in[0];
    const float* ln_gamma  = (const float*)d_in[1];
    const float* ln_beta   = (const float*)d_in[2];
    const float* w_expand  = (const float*)d_in[3];
    const float* freq_real = (const float*)d_in[4];
    // d_in[5] = freq_imag: provably unused (Re((r+ij)*x) for real x = r*x)
    const float* w_poly    = (const float*)d_in[6];
    const float* w_dw      = (const float*)d_in[7];
    const float* w_pw      = (const float*)d_in[8];
    const float* w_final   = (const float*)d_in[9];
    float* out = (float*)d_out;

    // workspace layout
    char* p = (char*)d_ws;
    __hip_bfloat16* f5   = (__hip_bfloat16*)p;  p += (size_t)C2 * Pp * 2;   // 64 MiB
    __hip_bfloat16* W1g_b = (__hip_bfloat16*)p; p += (size_t)C2 * Cc * 2;
    float* bias1 = (float*)p;                   p += (size_t)C2 * 4;
    float* wsum  = (float*)p;                   p += (size_t)C2 * 4;
    __hip_bfloat16* w_pw_b    = (__hip_bfloat16*)p;  p += (size_t)C2 * C2 * 2;
    __hip_bfloat16* w_final_b = (__hip_bfloat16*)p;  p += (size_t)Cc * C2 * 2;
    float* w_dw_p = (float*)p;                  p += (size_t)C2 * 12 * 4;

    combine_weights<<<dim3(C2), dim3(512), 0, stream>>>(
        w_expand, freq_real, w_poly, ln_gamma, ln_beta, W1g_b, bias1, wsum);

    prep_weights<<<dim3(409), dim3(256), 0, stream>>>(
        w_pw, w_final, w_dw, w_pw_b, w_final_b, w_dw_p);

    gemm1f<<<dim3(1024), dim3(512), 0, stream>>>(
        f, W1g_b, bias1, wsum, f5);

    fused_tail<<<dim3(1024), dim3(512), 0, stream>>>(
        f5, w_dw_p, w_pw_b, w_final_b, f, out);
}

// Round 5
// 337.018 us; speedup vs baseline: 1.3238x; 1.0189x over previous
//
#include <hip/hip_runtime.h>
#include <hip/hip_bf16.h>
#include <math.h>

// Problem constants
#define Bn 16
#define Cc 256
#define Hh 64
#define Ww 64
#define HW 4096
#define C2 512
#define Pp 65536          // Bn*HW
#define EPSc 1e-5f

typedef __attribute__((ext_vector_type(8))) short short8;
typedef __attribute__((ext_vector_type(4))) float floatx4;

// ---------------------------------------------------------------------------
// Kernel 0: combine weights, split-K (kh=0/1 halves the serial dep chain).
// ---------------------------------------------------------------------------
__global__ __launch_bounds__(512)
void combine_weights(const float* __restrict__ w_expand,
                     const float* __restrict__ freq_real,
                     const float* __restrict__ w_poly,
                     const float* __restrict__ gamma,
                     const float* __restrict__ beta,
                     __hip_bfloat16* __restrict__ W1g_b,
                     float* __restrict__ bias1,
                     float* __restrict__ wsum) {
    int o = blockIdx.x;
    int tid = threadIdx.x;
    int c = tid & 255;
    int kh = tid >> 8;           // 0/1: K-half
    float acc = 0.f;
    const float* wp = w_poly + (size_t)o * C2 + kh * 256;
    const float* fr = freq_real + kh * 256;
    const float* we = w_expand + (size_t)(kh * 256) * Cc + c;
    for (int m = 0; m < 256; ++m) {
        acc += wp[m] * fr[m] * we[(size_t)m * Cc];
    }
    __shared__ float part[512];
    __shared__ float redB[256];
    __shared__ float redG[256];
    part[tid] = acc;
    __syncthreads();
    if (tid < 256) {
        float a = part[tid] + part[tid + 256];
        float wg = a * gamma[c];
        W1g_b[(size_t)o * Cc + c] = __float2bfloat16(wg);
        redB[c] = a * beta[c];
        redG[c] = wg;
    }
    __syncthreads();
    for (int s = 128; s > 0; s >>= 1) {
        if (tid < s) { redB[tid] += redB[tid + s]; redG[tid] += redG[tid + s]; }
        __syncthreads();
    }
    if (tid == 0) { bias1[o] = redB[0]; wsum[o] = redG[0]; }
}

// ---------------------------------------------------------------------------
// Kernel 0b: merged weight prep — w_pw->bf16, w_final->bf16, pad w_dw.
// ---------------------------------------------------------------------------
__device__ inline void cvt4(const float* __restrict__ a,
                            __hip_bfloat16* __restrict__ o, int q) {
    float4 v = *(const float4*)&a[q * 4];
    __hip_bfloat16 r[4];
    r[0] = __float2bfloat16(v.x);
    r[1] = __float2bfloat16(v.y);
    r[2] = __float2bfloat16(v.z);
    r[3] = __float2bfloat16(v.w);
    *(uint2*)&o[q * 4] = *(const uint2*)r;
}

__global__ __launch_bounds__(256)
void prep_weights(const float* __restrict__ w_pw,
                  const float* __restrict__ w_final,
                  const float* __restrict__ w_dw,
                  __hip_bfloat16* __restrict__ w_pw_b,
                  __hip_bfloat16* __restrict__ w_final_b,
                  float* __restrict__ w_dw_p) {
    int i = blockIdx.x * 256 + threadIdx.x;
    if (i < 65536) {
        cvt4(w_pw, w_pw_b, i);
    } else if (i < 98304) {
        cvt4(w_final, w_final_b, i - 65536);
    } else {
        int j = i - 98304;
        if (j < C2 * 12) {
            int k = j / 12, l = j - k * 12;
            w_dw_p[j] = (l < 9) ? w_dw[k * 9 + l] : 0.f;
        }
    }
}

// ---------------------------------------------------------------------------
// Kernel 1 (fused prep+gemm): gemm1f — one block per (b,h) row.
// This round: f5 store goes through an LDS bounce so every global write is a
// full 128B line (kills the 8B-granule partial-line RMW write amplification).
// ---------------------------------------------------------------------------
#define XPAD 264   // LDS row pitch in bf16 (528 B = 33*16, 16B-aligned)

__global__ __launch_bounds__(512, 4)
void gemm1f(const float* __restrict__ f,
            const __hip_bfloat16* __restrict__ W1g_b,
            const float* __restrict__ bias1,
            const float* __restrict__ wsum,
            __hip_bfloat16* __restrict__ f5) {
    // manual carve: As 33792 | redS 8192 | redQ 8192 | muS 256 | rsS 256
    __shared__ __align__(16) char smem1[50688];
    __hip_bfloat16* As = (__hip_bfloat16*)smem1;
    float* redS = (float*)(smem1 + 33792);
    float* redQ = (float*)(smem1 + 41984);
    float* muS  = (float*)(smem1 + 50176);
    float* rsS  = (float*)(smem1 + 50432);

    int flat = blockIdx.x;       // 0..1023
    int b = flat >> 6;
    int h = flat & 63;
    int s0 = h * 64;

    int tid = threadIdx.x;
    int x = tid & 15;            // n-quad: positions x*4..x*4+3
    int cg = tid >> 4;           // 0..31 channel-pair group

    // ---- stage A + LN stats ----
    const float* fb = f + (size_t)b * Cc * HW + s0 + x * 4;
    unsigned* Asu = (unsigned*)&As[0];

    float lsum[4] = {0.f, 0.f, 0.f, 0.f};
    float lsq[4]  = {0.f, 0.f, 0.f, 0.f};
#pragma unroll
    for (int i = 0; i < 4; ++i) {
        int cp = i * 32 + cg;    // channel pair 0..127 -> channels 2cp, 2cp+1
        float4 v0 = *(const float4*)&fb[(size_t)(cp * 2) * HW];
        float4 v1 = *(const float4*)&fb[(size_t)(cp * 2 + 1) * HW];
        float a0[4] = {v0.x, v0.y, v0.z, v0.w};
        float a1[4] = {v1.x, v1.y, v1.z, v1.w};
#pragma unroll
        for (int j = 0; j < 4; ++j) {
            lsum[j] += a0[j] + a1[j];
            lsq[j]  += a0[j] * a0[j] + a1[j] * a1[j];
            unsigned pk = ((unsigned)__bfloat16_as_ushort(__float2bfloat16(a1[j])) << 16)
                        |  (unsigned)__bfloat16_as_ushort(__float2bfloat16(a0[j]));
            Asu[(size_t)(x * 4 + j) * (XPAD / 2) + cp] = pk;   // [n][k-pair]
        }
    }
#pragma unroll
    for (int j = 0; j < 4; ++j) {
        redS[cg * 64 + x * 4 + j] = lsum[j];
        redQ[cg * 64 + x * 4 + j] = lsq[j];
    }

    // ---- initial B prefetch, depth-2 (independent of LDS; before barrier) ----
    int lane = tid & 63, wave = tid >> 6;     // 8 waves
    int col = lane & 15, quad = lane >> 4;
    int c0w = wave * 64;                      // wave owns c0w..c0w+63 x all 64 pos
    const __hip_bfloat16* Bp = W1g_b + (size_t)(c0w + col) * Cc + quad * 8;
    short8 B0[4], B1[4];
#pragma unroll
    for (int j = 0; j < 4; ++j) {
        B0[j] = *(const short8*)(Bp + (size_t)j * 16 * Cc);
        B1[j] = *(const short8*)(Bp + (size_t)j * 16 * Cc + 32);
    }

    // epilogue scalars hoisted (tiny, L2-hot)
    float ws4[4], bi4[4];
#pragma unroll
    for (int j = 0; j < 4; ++j) {
        int c = c0w + j * 16 + col;
        ws4[j] = wsum[c];
        bi4[j] = bias1[c];
    }

    __syncthreads();
    if (tid < 64) {
        float s = 0.f, q = 0.f;
#pragma unroll
        for (int g = 0; g < 32; ++g) { s += redS[g * 64 + tid]; q += redQ[g * 64 + tid]; }
        float m = s * (1.0f / 256.0f);
        muS[tid] = m;
        rsS[tid] = rsqrtf(q * (1.0f / 256.0f) - m * m + EPSc);
    }
    __syncthreads();

    // ---- barrier-free K-loop, depth-2 B prefetch ----
    floatx4 acc[4][4];
#pragma unroll
    for (int i = 0; i < 4; ++i)
#pragma unroll
        for (int j = 0; j < 4; ++j)
            acc[i][j] = (floatx4){0.f, 0.f, 0.f, 0.f};

#pragma unroll
    for (int ks = 0; ks < 8; ++ks) {
        int k0 = ks * 32;
        short8 af[4];
#pragma unroll
        for (int i = 0; i < 4; ++i)
            af[i] = *(const short8*)&As[(size_t)(i * 16 + col) * XPAD + k0 + quad * 8];
        __builtin_amdgcn_s_setprio(1);
#pragma unroll
        for (int i = 0; i < 4; ++i)
#pragma unroll
            for (int j = 0; j < 4; ++j)
                acc[i][j] = __builtin_amdgcn_mfma_f32_16x16x32_bf16(
                    af[i], (ks & 1) ? B1[j] : B0[j], acc[i][j], 0, 0, 0);
        __builtin_amdgcn_s_setprio(0);
        if (ks + 2 < 8) {
#pragma unroll
            for (int j = 0; j < 4; ++j) {
                short8 v = *(const short8*)(Bp + (size_t)j * 16 * Cc + k0 + 64);
                if (ks & 1) B1[j] = v; else B0[j] = v;
            }
        }
    }

    // ---- epilogue: affine -> LDS bounce -> fully-coalesced 128B stores ----
    __syncthreads();             // all waves done reading As
    __hip_bfloat16* Wb = (__hip_bfloat16*)smem1;   // [256][72] bf16 = 36,864 B
    __hip_bfloat16* f5b = f5 + (size_t)b * C2 * HW + s0;
    int rr = tid >> 3;           // 0..63 : channel row within pass
    int rc = tid & 7;            // uint4 column
#pragma unroll
    for (int chunk = 0; chunk < 2; ++chunk) {
        if ((wave >> 2) == chunk) {
            int cbase = c0w & 255;
#pragma unroll
            for (int i = 0; i < 4; ++i) {
                int pl = i * 16 + quad * 4;
                float4 mu4 = *(const float4*)&muS[pl];
                float4 rs4 = *(const float4*)&rsS[pl];
                float mu_[4] = {mu4.x, mu4.y, mu4.z, mu4.w};
                float rs_[4] = {rs4.x, rs4.y, rs4.z, rs4.w};
#pragma unroll
                for (int j = 0; j < 4; ++j) {
                    int cl = cbase + j * 16 + col;
                    __hip_bfloat16 v4[4];
#pragma unroll
                    for (int r = 0; r < 4; ++r) {
                        float v = (acc[i][j][r] - mu_[r] * ws4[j]) * rs_[r] + bi4[j];
                        v4[r] = __float2bfloat16(v);
                    }
                    *(uint2*)&Wb[(size_t)cl * 72 + pl] = *(const uint2*)v4;
                }
            }
        }
        __syncthreads();
#pragma unroll
        for (int pass = 0; pass < 4; ++pass) {
            int cl = pass * 64 + rr;
            uint4 v = *(const uint4*)&Wb[(size_t)cl * 72 + rc * 8];
            *(uint4*)&f5b[(size_t)(chunk * 256 + cl) * HW + rc * 8] = v;
        }
        if (chunk == 0) __syncthreads();
    }
}

// ---------------------------------------------------------------------------
// Kernel 3: fused tail. This round:
//  - tT XOR swizzle (element e of row r stored at e ^ (((r>>4)&3)<<4)):
//    phase-0 scalar stores become bank-conflict-free (key = t4, per-lane);
//    phase-1/2 reads and gating writes use key = nt (uniform per inst, free).
//  - out epilogue bounced through LDS (f32, pitch 68) -> fully coalesced
//    float4 residual-load/add/store (kills partial-line RMW write amp).
// ---------------------------------------------------------------------------
#define TPITCH 520

#define P0_LOAD(dst, itc) do {                                               \
    int kk_ = (itc) * 128 + kb;                                              \
    _Pragma("unroll")                                                        \
    for (int dy_ = 0; dy_ < 3; ++dy_) {                                      \
        int hh_ = h + dy_ - 1;                                               \
        if ((unsigned)hh_ < Hh) {                                            \
            const __hip_bfloat16* row_ = f5b + (size_t)kk_ * HW + hh_ * Ww + w16; \
            dst[dy_][0] = *(const uint4*)&row_[0];                           \
            dst[dy_][1] = *(const uint4*)&row_[8];                           \
        } else {                                                             \
            dst[dy_][0] = make_uint4(0, 0, 0, 0);                            \
            dst[dy_][1] = make_uint4(0, 0, 0, 0);                            \
        }                                                                    \
    } } while (0)

__global__ __launch_bounds__(512, 4)
void fused_tail(const __hip_bfloat16* __restrict__ f5,
                const float* __restrict__ w_dw_p,
                const __hip_bfloat16* __restrict__ w_pw_b,
                const __hip_bfloat16* __restrict__ w_final_b,
                const float* __restrict__ f,
                float* __restrict__ out) {
    // union: tT [64][520] bf16 (66,560 B) for phases 0-2;
    //        Lf [256][68] f32 (69,632 B) for the out-bounce epilogue.
    __shared__ __align__(16) char smem[69632];
    __hip_bfloat16* tT = (__hip_bfloat16*)smem;
    float* Lf = (float*)smem;

    int flat = blockIdx.x;         // 0..1023
    int xcd = flat & 7;
    int slot = flat >> 3;          // 0..127
    int hb = slot & 7;
    int b  = slot >> 3;            // 0..15
    int h  = xcd * 8 + hb;

    int tid = threadIdx.x;
    int lane = tid & 63;
    int wave = tid >> 6;           // 0..7
    int col = lane & 15;
    int quad = lane >> 4;

    // ---- phase 0: depthwise 3x3 -> tT[pos][ch] (bf16, swizzled), depth-2 ----
    const __hip_bfloat16* f5b = f5 + (size_t)b * C2 * HW;
    int t4 = tid & 3;
    int kb = tid >> 2;             // 0..127
    int w16 = t4 * 16;

    uint4 bA[3][2], bB[3][2];
    P0_LOAD(bA, 0);
    P0_LOAD(bB, 1);

#pragma unroll
    for (int it = 0; it < 4; ++it) {
        int k = it * 128 + kb;
        const float4* wd4 = (const float4*)(w_dw_p + (size_t)k * 12);
        float4 wa = wd4[0], wb = wd4[1], wc2 = wd4[2];
        float wreg[9] = {wa.x, wa.y, wa.z, wa.w, wb.x, wb.y, wb.z, wb.w, wc2.x};
        float acc16[16] = {};
#pragma unroll
        for (int dy = 0; dy < 3; ++dy) {
            const __hip_bfloat16* pv =
                (const __hip_bfloat16*)((it & 1) ? &bB[dy][0] : &bA[dy][0]);
            float cv[16];
#pragma unroll
            for (int j = 0; j < 16; ++j) cv[j] = __bfloat162float(pv[j]);
            float l_in = __shfl_up(cv[15], 1);
            float r_in = __shfl_down(cv[0], 1);
            if (t4 == 0) l_in = 0.f;     // w = -1 -> zero pad
            if (t4 == 3) r_in = 0.f;     // w = 64 -> zero pad
            float win[18];
            win[0] = l_in;
#pragma unroll
            for (int j = 0; j < 16; ++j) win[j + 1] = cv[j];
            win[17] = r_in;
#pragma unroll
            for (int j = 0; j < 16; ++j)
                acc16[j] += wreg[dy * 3 + 0] * win[j] +
                            wreg[dy * 3 + 1] * win[j + 1] +
                            wreg[dy * 3 + 2] * win[j + 2];
        }
        if (it + 2 < 4) {
            if (it & 1) { P0_LOAD(bB, it + 2); } else { P0_LOAD(bA, it + 2); }
        }
        // swizzled store: row = w16+j (row>>4 == t4), element k ^ (t4<<4)
        int ksw = k ^ (t4 << 4);
#pragma unroll
        for (int j = 0; j < 16; ++j)
            tT[(size_t)(w16 + j) * TPITCH + ksw] = __float2bfloat16(acc16[j]);
    }

    // ---- phase 1: g = w_pw @ t; wave = 64 out x 64 pos, depth-2 A prefetch ----
    int wm0 = wave * 64;
    const __hip_bfloat16* Ap = w_pw_b + (size_t)(wm0 + col) * C2 + quad * 8;
    short8 A0[4], A1[4];
#pragma unroll
    for (int mt = 0; mt < 4; ++mt)
        A0[mt] = *(const short8*)(Ap + (size_t)mt * 16 * C2);

    __syncthreads();   // phase 0 done

#pragma unroll
    for (int mt = 0; mt < 4; ++mt)
        A1[mt] = *(const short8*)(Ap + (size_t)mt * 16 * C2 + 32);

    floatx4 acc[4][4];
#pragma unroll
    for (int mt = 0; mt < 4; ++mt)
#pragma unroll
        for (int nt = 0; nt < 4; ++nt)
            acc[mt][nt] = (floatx4){0.f, 0.f, 0.f, 0.f};

#pragma unroll
    for (int ks = 0; ks < 16; ++ks) {
        int k0 = ks * 32;
        short8 bfr[4];
#pragma unroll
        for (int nt = 0; nt < 4; ++nt)
            bfr[nt] = *(const short8*)&tT[(size_t)(nt * 16 + col) * TPITCH +
                                          ((k0 + quad * 8) ^ (nt << 4))];
        __builtin_amdgcn_s_setprio(1);
#pragma unroll
        for (int mt = 0; mt < 4; ++mt)
#pragma unroll
            for (int nt = 0; nt < 4; ++nt)
                acc[mt][nt] = __builtin_amdgcn_mfma_f32_16x16x32_bf16(
                    (ks & 1) ? A1[mt] : A0[mt], bfr[nt], acc[mt][nt], 0, 0, 0);
        __builtin_amdgcn_s_setprio(0);
        if (ks + 2 < 16) {
#pragma unroll
            for (int mt = 0; mt < 4; ++mt) {
                short8 v = *(const short8*)(Ap + (size_t)mt * 16 * C2 + k0 + 64);
                if (ks & 1) A1[mt] = v; else A0[mt] = v;
            }
        }
    }
    __syncthreads();   // everyone done reading tT (as t)

    // ---- gating: f7 = gelu(g)*g -> back into tT (same swizzle, key = nt) ----
#pragma unroll
    for (int mt = 0; mt < 4; ++mt)
#pragma unroll
        for (int nt = 0; nt < 4; ++nt) {
            __hip_bfloat16 v4[4];
#pragma unroll
            for (int r = 0; r < 4; ++r) {
                float v = acc[mt][nt][r];
                float gl = 0.5f * v * (1.0f + erff(v * 0.70710678118f));
                v4[r] = __float2bfloat16(gl * v);
            }
            *(uint2*)&tT[(size_t)(nt * 16 + col) * TPITCH +
                         ((wm0 + mt * 16 + quad * 4) ^ (nt << 4))] = *(const uint2*)v4;
        }

    // ---- phase 2: f8 = w_final @ f7; wave = 32 out x 64 pos; depth-2 ----
    int wm2 = wave * 32;
    const __hip_bfloat16* Af = w_final_b + (size_t)(wm2 + col) * C2 + quad * 8;
    short8 C0[2], C1[2];
#pragma unroll
    for (int mt = 0; mt < 2; ++mt)
        C0[mt] = *(const short8*)(Af + (size_t)mt * 16 * C2);

    __syncthreads();   // f7 fully written

#pragma unroll
    for (int mt = 0; mt < 2; ++mt)
        C1[mt] = *(const short8*)(Af + (size_t)mt * 16 * C2 + 32);

    floatx4 acc2[2][4];
#pragma unroll
    for (int mt = 0; mt < 2; ++mt)
#pragma unroll
        for (int nt = 0; nt < 4; ++nt)
            acc2[mt][nt] = (floatx4){0.f, 0.f, 0.f, 0.f};

#pragma unroll
    for (int ks = 0; ks < 16; ++ks) {
        int k0 = ks * 32;
        short8 bfr[4];
#pragma unroll
        for (int nt = 0; nt < 4; ++nt)
            bfr[nt] = *(const short8*)&tT[(size_t)(nt * 16 + col) * TPITCH +
                                          ((k0 + quad * 8) ^ (nt << 4))];
        __builtin_amdgcn_s_setprio(1);
#pragma unroll
        for (int mt = 0; mt < 2; ++mt)
#pragma unroll
            for (int nt = 0; nt < 4; ++nt)
                acc2[mt][nt] = __builtin_amdgcn_mfma_f32_16x16x32_bf16(
                    (ks & 1) ? C1[mt] : C0[mt], bfr[nt], acc2[mt][nt], 0, 0, 0);
        __builtin_amdgcn_s_setprio(0);
        if (ks + 2 < 16) {
#pragma unroll
            for (int mt = 0; mt < 2; ++mt) {
                short8 v = *(const short8*)(Af + (size_t)mt * 16 * C2 + k0 + 64);
                if (ks & 1) C1[mt] = v; else C0[mt] = v;
            }
        }
    }

    // ---- epilogue: f8 -> LDS (f32, pitch 68) -> coalesced out = f + f8 ----
    __syncthreads();   // all waves done reading tT (as f7)
#pragma unroll
    for (int mt = 0; mt < 2; ++mt)
#pragma unroll
        for (int nt = 0; nt < 4; ++nt)
#pragma unroll
            for (int r = 0; r < 4; ++r) {
                int m = wm2 + mt * 16 + quad * 4 + r;
                int n = nt * 16 + col;
                Lf[(size_t)m * 68 + n] = acc2[mt][nt][r];
            }
    __syncthreads();

    const float* fb = f + (size_t)b * Cc * HW + h * Ww;
    float* ob = out + (size_t)b * Cc * HW + h * Ww;
    int pr = tid >> 4;      // 0..31 : channel row within pass
    int pc = tid & 15;      // float4 column (16 x 16B = 256B per row)
#pragma unroll
    for (int pass = 0; pass < 8; ++pass) {
        int m = pass * 32 + pr;
        float4 v = *(const float4*)&Lf[(size_t)m * 68 + pc * 4];
        float4 rr4 = *(const float4*)&fb[(size_t)m * HW + pc * 4];
        v.x += rr4.x; v.y += rr4.y; v.z += rr4.z; v.w += rr4.w;
        *(float4*)&ob[(size_t)m * HW + pc * 4] = v;
    }
}

// ---------------------------------------------------------------------------
extern "C" void kernel_launch(void* const* d_in, const int* in_sizes, int n_in,
                              void* d_out, int out_size, void* d_ws, size_t ws_size,
                              hipStream_t stream) {
    const float* f         = (const float*)d_in[0];
    const float* ln_gamma  = (const float*)d_in[1];
    const float* ln_beta   = (const float*)d_in[2];
    const float* w_expand  = (const float*)d_in[3];
    const float* freq_real = (const float*)d_in[4];
    // d_in[5] = freq_imag: provably unused (Re((r+ij)*x) for real x = r*x)
    const float* w_poly    = (const float*)d_in[6];
    const float* w_dw      = (const float*)d_in[7];
    const float* w_pw      = (const float*)d_in[8];
    const float* w_final   = (const float*)d_in[9];
    float* out = (float*)d_out;

    // workspace layout
    char* p = (char*)d_ws;
    __hip_bfloat16* f5   = (__hip_bfloat16*)p;  p += (size_t)C2 * Pp * 2;   // 64 MiB
    __hip_bfloat16* W1g_b = (__hip_bfloat16*)p; p += (size_t)C2 * Cc * 2;
    float* bias1 = (float*)p;                   p += (size_t)C2 * 4;
    float* wsum  = (float*)p;                   p += (size_t)C2 * 4;
    __hip_bfloat16* w_pw_b    = (__hip_bfloat16*)p;  p += (size_t)C2 * C2 * 2;
    __hip_bfloat16* w_final_b = (__hip_bfloat16*)p;  p += (size_t)Cc * C2 * 2;
    float* w_dw_p = (float*)p;                  p += (size_t)C2 * 12 * 4;

    combine_weights<<<dim3(C2), dim3(512), 0, stream>>>(
        w_expand, freq_real, w_poly, ln_gamma, ln_beta, W1g_b, bias1, wsum);

    prep_weights<<<dim3(409), dim3(256), 0, stream>>>(
        w_pw, w_final, w_dw, w_pw_b, w_final_b, w_dw_p);

    gemm1f<<<dim3(1024), dim3(512), 0, stream>>>(
        f, W1g_b, bias1, wsum, f5);

    fused_tail<<<dim3(1024), dim3(512), 0, stream>>>(
        f5, w_dw_p, w_pw_b, w_final_b, f, out);
}